// Round 2
// baseline (19761.285 us; speedup 1.0000x reference)
//
#include <hip/hip_runtime.h>
#include <math.h>

// Problem constants
#define Bn   16
#define TINn 112
#define Hn   16
#define Wn   16
#define CINn 6
#define Tn   28
#define CEMBn 24
#define Fn   64
// Gate channels = 4*F = 256

// ---------------- embed: x[B,112,16,16,6] -> xe[B,28,16,16,24] ----------------
__global__ void embed_kernel(const float* __restrict__ x, float* __restrict__ xe) {
    int idx = blockIdx.x * blockDim.x + threadIdx.x;
    const int total = Bn * Tn * Hn * Wn * CEMBn;
    if (idx >= total) return;
    int ce = idx % CEMBn;
    int r = idx / CEMBn;
    int w = r % Wn; r /= Wn;
    int h = r % Hn; r /= Hn;
    int t = r % Tn;
    int b = r / Tn;
    int ti = t * 4 + ce / CINn;   // 24 = 4*6
    int ci = ce % CINn;
    xe[idx] = x[(((b * TINn + ti) * Hn + h) * Wn + w) * CINn + ci];
}

// ---------------- one ConvLSTM timestep, both directions ----------------
// xin:  [B,T,H,W,CIN]  layer input (layer0: xe CIN=24, layer1: h0 CIN=128)
// hout: [B,T,H,W,128]  layer output; fwd writes ch [0:64), bwd ch [64:128).
//                      Previous timestep's slot doubles as the recurrent input.
// c_ws: [2,B,H,W,64]   cell state (initialized when t==0; poison-safe)
template<int CIN>
__global__ __launch_bounds__(256)
void lstm_step(const float* __restrict__ xin,
               const float* __restrict__ wx_f, const float* __restrict__ wh_f,
               const float* __restrict__ b_f,
               const float* __restrict__ wx_b, const float* __restrict__ wh_b,
               const float* __restrict__ b_b,
               float* __restrict__ hout,
               float* __restrict__ c_ws,
               int t) {
    const int dir = blockIdx.y;            // 0 = fwd, 1 = bwd
    const int tid = threadIdx.x;
    const int f = tid & 63;                // filter 0..63
    const int s = blockIdx.x * 4 + (tid >> 6);   // spatial 0..4095
    const int w = s & 15;
    const int h = (s >> 4) & 15;
    const int b = s >> 8;

    const int t_orig = dir ? (Tn - 1 - t) : t;
    const float* wx = dir ? wx_b : wx_f;
    const float* wh = dir ? wh_b : wh_f;
    const float* bb = dir ? b_b : b_f;

    float z0 = bb[f];          // i
    float z1 = bb[64 + f];     // f
    float z2 = bb[128 + f];    // g
    float z3 = bb[192 + f];    // o

    // input-to-hidden conv (3x3, SAME)
    for (int kh = 0; kh < 3; ++kh) {
        int hh = h + kh - 1;
        if ((unsigned)hh >= (unsigned)Hn) continue;
        for (int kw = 0; kw < 3; ++kw) {
            int ww = w + kw - 1;
            if ((unsigned)ww >= (unsigned)Wn) continue;
            const float* xp = xin + (((((size_t)b * Tn + t_orig) * Hn + hh) * Wn + ww) * CIN);
            const float* wp = wx + ((size_t)(kh * 3 + kw) * CIN) * 256 + f;
            #pragma unroll 4
            for (int ci = 0; ci < CIN; ++ci) {
                float v = xp[ci];
                z0 = fmaf(v, wp[ci * 256],       z0);
                z1 = fmaf(v, wp[ci * 256 + 64],  z1);
                z2 = fmaf(v, wp[ci * 256 + 128], z2);
                z3 = fmaf(v, wp[ci * 256 + 192], z3);
            }
        }
    }

    // hidden-to-hidden conv (3x3, SAME) against previous timestep's h
    if (t > 0) {
        const int tp = dir ? (t_orig + 1) : (t_orig - 1);
        for (int kh = 0; kh < 3; ++kh) {
            int hh = h + kh - 1;
            if ((unsigned)hh >= (unsigned)Hn) continue;
            for (int kw = 0; kw < 3; ++kw) {
                int ww = w + kw - 1;
                if ((unsigned)ww >= (unsigned)Wn) continue;
                const float* hp = hout + ((((size_t)b * Tn + tp) * Hn + hh) * Wn + ww) * 128 + dir * 64;
                const float* wp = wh + ((size_t)(kh * 3 + kw) * 64) * 256 + f;
                #pragma unroll 4
                for (int ci = 0; ci < 64; ++ci) {
                    float v = hp[ci];
                    z0 = fmaf(v, wp[ci * 256],       z0);
                    z1 = fmaf(v, wp[ci * 256 + 64],  z1);
                    z2 = fmaf(v, wp[ci * 256 + 128], z2);
                    z3 = fmaf(v, wp[ci * 256 + 192], z3);
                }
            }
        }
    }

    float gi = 1.0f / (1.0f + expf(-z0));
    float gf = 1.0f / (1.0f + expf(-z1));
    float gg = tanhf(z2);
    float go = 1.0f / (1.0f + expf(-z3));

    const int cidx = (((dir * Bn + b) * (Hn * Wn)) + h * Wn + w) * 64 + f;
    float cp = (t == 0) ? 0.0f : c_ws[cidx];
    float c = gf * cp + gi * gg;
    float hv = go * tanhf(c);
    c_ws[cidx] = c;

    hout[((((size_t)b * Tn + t_orig) * Hn + h) * Wn + w) * 128 + dir * 64 + f] = hv;
}

// ---------------- final TimeDistributed Conv2D: [B,T,H,W,128] -> [B,T,H,W,1] ----------------
__global__ void out_conv(const float* __restrict__ h1,
                         const float* __restrict__ wout,
                         const float* __restrict__ bout,
                         float* __restrict__ out) {
    int idx = blockIdx.x * blockDim.x + threadIdx.x;   // B*T*H*W = 114688
    if (idx >= Bn * Tn * Hn * Wn) return;
    int w = idx & 15;
    int h = (idx >> 4) & 15;
    int r = idx >> 8;
    int t = r % Tn;
    int b = r / Tn;

    float acc = bout[0];
    for (int kh = 0; kh < 3; ++kh) {
        int hh = h + kh - 1;
        if ((unsigned)hh >= (unsigned)Hn) continue;
        for (int kw = 0; kw < 3; ++kw) {
            int ww = w + kw - 1;
            if ((unsigned)ww >= (unsigned)Wn) continue;
            const float* hp = h1 + ((((size_t)b * Tn + t) * Hn + hh) * Wn + ww) * 128;
            const float* wp = wout + (kh * 3 + kw) * 128;
            #pragma unroll 8
            for (int ci = 0; ci < 128; ++ci)
                acc = fmaf(hp[ci], wp[ci], acc);
        }
    }
    out[idx] = acc;
}

extern "C" void kernel_launch(void* const* d_in, const int* in_sizes, int n_in,
                              void* d_out, int out_size, void* d_ws, size_t ws_size,
                              hipStream_t stream) {
    const float* x    = (const float*)d_in[0];
    const float* wx0f = (const float*)d_in[1];
    const float* wh0f = (const float*)d_in[2];
    const float* b0f  = (const float*)d_in[3];
    const float* wx0b = (const float*)d_in[4];
    const float* wh0b = (const float*)d_in[5];
    const float* b0b  = (const float*)d_in[6];
    const float* wx1f = (const float*)d_in[7];
    const float* wh1f = (const float*)d_in[8];
    const float* b1f  = (const float*)d_in[9];
    const float* wx1b = (const float*)d_in[10];
    const float* wh1b = (const float*)d_in[11];
    const float* b1b  = (const float*)d_in[12];
    const float* wout = (const float*)d_in[13];
    const float* bout = (const float*)d_in[14];
    float* out = (float*)d_out;

    // workspace layout (floats)
    const size_t XE_N = (size_t)Bn * Tn * Hn * Wn * CEMBn;   //  2,752,512
    const size_t H_N  = (size_t)Bn * Tn * Hn * Wn * 128;     // 14,680,064
    const size_t C_N  = (size_t)2 * Bn * Hn * Wn * 64;       //    524,288
    float* xe  = (float*)d_ws;
    float* h0  = xe + XE_N;
    float* h1  = h0 + H_N;
    float* cws = h1 + H_N;
    (void)ws_size; (void)n_in; (void)in_sizes; (void)out_size; (void)C_N;

    // 1) embed
    {
        int total = (int)XE_N;
        embed_kernel<<<(total + 255) / 256, 256, 0, stream>>>(x, xe);
    }

    // 2) layer 0 (CIN=24), both directions per launch
    for (int t = 0; t < Tn; ++t) {
        lstm_step<CEMBn><<<dim3(1024, 2), 256, 0, stream>>>(
            xe, wx0f, wh0f, b0f, wx0b, wh0b, b0b, h0, cws, t);
    }

    // 3) layer 1 (CIN=128)
    for (int t = 0; t < Tn; ++t) {
        lstm_step<128><<<dim3(1024, 2), 256, 0, stream>>>(
            h0, wx1f, wh1f, b1f, wx1b, wh1b, b1b, h1, cws, t);
    }

    // 4) output conv
    out_conv<<<(Bn * Tn * Hn * Wn + 255) / 256, 256, 0, stream>>>(h1, wout, bout, out);
}

// Round 3
// 5712.202 us; speedup vs baseline: 3.4595x; 3.4595x over previous
//
#include <hip/hip_runtime.h>
#include <math.h>

// Problem constants
#define Bn   16
#define TINn 112
#define Hn   16
#define Wn   16
#define CINn 6
#define Tn   28
#define CEMBn 24
#define Fn   64
// Gate channels = 4*F = 256

// ---------------- embed: x[B,112,16,16,6] -> xe[B,28,16,16,24] ----------------
__global__ void embed_kernel(const float* __restrict__ x, float* __restrict__ xe) {
    int idx = blockIdx.x * blockDim.x + threadIdx.x;
    const int total = Bn * Tn * Hn * Wn * CEMBn;
    if (idx >= total) return;
    int ce = idx % CEMBn;
    int r = idx / CEMBn;
    int w = r % Wn; r /= Wn;
    int h = r % Hn; r /= Hn;
    int t = r % Tn;
    int b = r / Tn;
    int ti = t * 4 + ce / CINn;   // 24 = 4*6
    int ci = ce % CINn;
    xe[idx] = x[(((b * TINn + ti) * Hn + h) * Wn + w) * CINn + ci];
}

// ---------------- GEMM chunk: stage W[ROWS][256] + A[ROWS][16] in LDS, accumulate ----------------
// Block tile: 16 spatial (one image row) x 256 gate outputs.
// Thread (qo = tid&63, ms = tid>>6): outputs o = qo*4..qo*4+3, spatial m = ms*4..ms*4+3.
// Per k: 1 ds_read_b128 of W (unique across lanes) + 1 ds_read_b128 of A (wave-uniform) + 16 FMA.
template<int ROWS>
__device__ __forceinline__ void chunk_gemm(
    float (&Ws)[32][256], float (&As)[32][20], float (&acc)[4][4],
    const float* __restrict__ arow, int pixstride, int choff,
    const float* __restrict__ wrow, int kw, int tid, int qo, int ms)
{
    __syncthreads();   // protect LDS from previous chunk's readers
    // stage W chunk (contiguous ROWS*256 floats), fully coalesced float4
    {
        const float4* wsrc = (const float4*)wrow;
        float4* wdst = (float4*)&Ws[0][0];
        #pragma unroll
        for (int i = 0; i < (ROWS * 64) / 256; ++i)
            wdst[i * 256 + tid] = wsrc[i * 256 + tid];
    }
    // stage A chunk transposed: As[ci][m] = input pixel (m+kw-1) channel choff+ci (0 if OOB)
    {
        const int ci = tid & 31;
        const int mm = tid >> 5;
        if (ci < ROWS) {
            #pragma unroll
            for (int mi = 0; mi < 2; ++mi) {
                const int m = mm + (mi << 3);
                const int ww = m + kw - 1;
                As[ci][m] = ((unsigned)ww < 16u) ? arow[ww * pixstride + choff + ci] : 0.0f;
            }
        }
    }
    __syncthreads();
    #pragma unroll
    for (int k = 0; k < ROWS; ++k) {
        const float4 w4 = *(const float4*)&Ws[k][qo << 2];
        const float4 a4 = *(const float4*)&As[k][ms << 2];
        acc[0][0] = fmaf(a4.x, w4.x, acc[0][0]);
        acc[0][1] = fmaf(a4.x, w4.y, acc[0][1]);
        acc[0][2] = fmaf(a4.x, w4.z, acc[0][2]);
        acc[0][3] = fmaf(a4.x, w4.w, acc[0][3]);
        acc[1][0] = fmaf(a4.y, w4.x, acc[1][0]);
        acc[1][1] = fmaf(a4.y, w4.y, acc[1][1]);
        acc[1][2] = fmaf(a4.y, w4.z, acc[1][2]);
        acc[1][3] = fmaf(a4.y, w4.w, acc[1][3]);
        acc[2][0] = fmaf(a4.z, w4.x, acc[2][0]);
        acc[2][1] = fmaf(a4.z, w4.y, acc[2][1]);
        acc[2][2] = fmaf(a4.z, w4.z, acc[2][2]);
        acc[2][3] = fmaf(a4.z, w4.w, acc[2][3]);
        acc[3][0] = fmaf(a4.w, w4.x, acc[3][0]);
        acc[3][1] = fmaf(a4.w, w4.y, acc[3][1]);
        acc[3][2] = fmaf(a4.w, w4.z, acc[3][2]);
        acc[3][3] = fmaf(a4.w, w4.w, acc[3][3]);
    }
}

// ---------------- one ConvLSTM timestep (GEMM-tiled), both directions ----------------
// xin:  [B,T,H,W,CIN_X]  layer input
// hout: [B,T,H,W,128]    fwd ch [0:64), bwd ch [64:128). prev timestep slot = recurrent input.
// c_ws: [2,B,H,W,64]     cell state
template<int CIN_X>
__global__ __launch_bounds__(256)
void lstm_step_gemm(const float* __restrict__ xin,
                    const float* __restrict__ wx_f, const float* __restrict__ wh_f,
                    const float* __restrict__ b_f,
                    const float* __restrict__ wx_b, const float* __restrict__ wh_b,
                    const float* __restrict__ b_b,
                    float* __restrict__ hout,
                    float* __restrict__ c_ws,
                    int t)
{
    __shared__ __align__(16) float Ws[32][256];   // 32 KB weight chunk
    __shared__ __align__(16) float As[32][20];    // im2col tile, padded
    __shared__ float Zs[256][17];                 // gate pre-activations, padded

    const int tid  = threadIdx.x;
    const int dir  = blockIdx.y;       // 0 fwd, 1 bwd
    const int sblk = blockIdx.x;       // 0..255 = b*16 + h (one image row per block)
    const int b  = sblk >> 4;
    const int h  = sblk & 15;
    const int qo = tid & 63;
    const int ms = tid >> 6;

    const int t_orig = dir ? (Tn - 1 - t) : t;
    const float* wx   = dir ? wx_b : wx_f;
    const float* wh   = dir ? wh_b : wh_f;
    const float* bias = dir ? b_b  : b_f;

    float acc[4][4];
    {
        const float4 bq = *(const float4*)(bias + (qo << 2));
        #pragma unroll
        for (int m2 = 0; m2 < 4; ++m2) {
            acc[m2][0] = bq.x; acc[m2][1] = bq.y; acc[m2][2] = bq.z; acc[m2][3] = bq.w;
        }
    }

    // ---- x2h ----
    const float* ximg = xin + ((size_t)b * Tn + t_orig) * (16 * 16 * CIN_X);
    for (int kh = 0; kh < 3; ++kh) {
        const int hh = h + kh - 1;
        if ((unsigned)hh >= 16u) continue;               // block-uniform
        const float* arow = ximg + hh * (16 * CIN_X);
        for (int kw = 0; kw < 3; ++kw) {
            if (CIN_X == 24) {
                chunk_gemm<24>(Ws, As, acc, arow, CIN_X, 0,
                               wx + (size_t)((kh * 3 + kw) * CIN_X) * 256, kw, tid, qo, ms);
            } else {
                for (int ci0 = 0; ci0 < CIN_X; ci0 += 32)
                    chunk_gemm<32>(Ws, As, acc, arow, CIN_X, ci0,
                                   wx + (size_t)((kh * 3 + kw) * CIN_X + ci0) * 256, kw, tid, qo, ms);
            }
        }
    }

    // ---- h2h (skip at t==0: h0 = 0) ----
    if (t > 0) {
        const int tp = dir ? (t_orig + 1) : (t_orig - 1);
        const float* himg = hout + ((size_t)b * Tn + tp) * (16 * 16 * 128) + dir * 64;
        for (int kh = 0; kh < 3; ++kh) {
            const int hh = h + kh - 1;
            if ((unsigned)hh >= 16u) continue;
            const float* arow = himg + hh * (16 * 128);
            for (int kw = 0; kw < 3; ++kw)
                for (int ci0 = 0; ci0 < 64; ci0 += 32)
                    chunk_gemm<32>(Ws, As, acc, arow, 128, ci0,
                                   wh + (size_t)((kh * 3 + kw) * 64 + ci0) * 256, kw, tid, qo, ms);
        }
    }

    // ---- exchange z so each thread gets all 4 gates of 4 consecutive filters ----
    #pragma unroll
    for (int m2 = 0; m2 < 4; ++m2)
        #pragma unroll
        for (int r = 0; r < 4; ++r)
            Zs[(qo << 2) + r][(ms << 2) + m2] = acc[m2][r];
    __syncthreads();

    const int m  = tid >> 4;           // w coordinate 0..15
    const int f0 = (tid & 15) << 2;    // filter quad base

    float zz[4][4];
    #pragma unroll
    for (int g = 0; g < 4; ++g)
        #pragma unroll
        for (int i = 0; i < 4; ++i)
            zz[g][i] = Zs[(g << 6) + f0 + i][m];

    float* cp = c_ws + ((size_t)((dir * 16 + b) * 256) + (h << 4) + m) * 64 + f0;
    float cov[4] = {0.f, 0.f, 0.f, 0.f};
    if (t > 0) {
        const float4 cold = *(const float4*)cp;
        cov[0] = cold.x; cov[1] = cold.y; cov[2] = cold.z; cov[3] = cold.w;
    }

    float cn[4], hn[4];
    #pragma unroll
    for (int i = 0; i < 4; ++i) {
        const float gi = 1.0f / (1.0f + expf(-zz[0][i]));
        const float gf = 1.0f / (1.0f + expf(-zz[1][i]));
        const float gg = tanhf(zz[2][i]);
        const float go = 1.0f / (1.0f + expf(-zz[3][i]));
        const float c  = gf * cov[i] + gi * gg;
        cn[i] = c;
        hn[i] = go * tanhf(c);
    }
    *(float4*)cp = make_float4(cn[0], cn[1], cn[2], cn[3]);
    float* hp = hout + (((size_t)b * Tn + t_orig) * 256 + (h << 4) + m) * 128 + (dir << 6) + f0;
    *(float4*)hp = make_float4(hn[0], hn[1], hn[2], hn[3]);
}

// ---------------- final TimeDistributed Conv2D: [B,T,H,W,128] -> [B,T,H,W,1] ----------------
__global__ void out_conv(const float* __restrict__ h1,
                         const float* __restrict__ wout,
                         const float* __restrict__ bout,
                         float* __restrict__ out) {
    int idx = blockIdx.x * blockDim.x + threadIdx.x;   // B*T*H*W = 114688
    if (idx >= Bn * Tn * Hn * Wn) return;
    int w = idx & 15;
    int h = (idx >> 4) & 15;
    int r = idx >> 8;
    int t = r % Tn;
    int b = r / Tn;

    float acc = bout[0];
    for (int kh = 0; kh < 3; ++kh) {
        int hh = h + kh - 1;
        if ((unsigned)hh >= (unsigned)Hn) continue;
        for (int kw = 0; kw < 3; ++kw) {
            int ww = w + kw - 1;
            if ((unsigned)ww >= (unsigned)Wn) continue;
            const float* hp = h1 + ((((size_t)b * Tn + t) * Hn + hh) * Wn + ww) * 128;
            const float* wp = wout + (kh * 3 + kw) * 128;
            #pragma unroll 8
            for (int ci = 0; ci < 128; ++ci)
                acc = fmaf(hp[ci], wp[ci], acc);
        }
    }
    out[idx] = acc;
}

extern "C" void kernel_launch(void* const* d_in, const int* in_sizes, int n_in,
                              void* d_out, int out_size, void* d_ws, size_t ws_size,
                              hipStream_t stream) {
    const float* x    = (const float*)d_in[0];
    const float* wx0f = (const float*)d_in[1];
    const float* wh0f = (const float*)d_in[2];
    const float* b0f  = (const float*)d_in[3];
    const float* wx0b = (const float*)d_in[4];
    const float* wh0b = (const float*)d_in[5];
    const float* b0b  = (const float*)d_in[6];
    const float* wx1f = (const float*)d_in[7];
    const float* wh1f = (const float*)d_in[8];
    const float* b1f  = (const float*)d_in[9];
    const float* wx1b = (const float*)d_in[10];
    const float* wh1b = (const float*)d_in[11];
    const float* b1b  = (const float*)d_in[12];
    const float* wout = (const float*)d_in[13];
    const float* bout = (const float*)d_in[14];
    float* out = (float*)d_out;

    // workspace layout (floats)
    const size_t XE_N = (size_t)Bn * Tn * Hn * Wn * CEMBn;   //  2,752,512
    const size_t H_N  = (size_t)Bn * Tn * Hn * Wn * 128;     // 14,680,064
    float* xe  = (float*)d_ws;
    float* h0  = xe + XE_N;
    float* h1  = h0 + H_N;
    float* cws = h1 + H_N;
    (void)ws_size; (void)n_in; (void)in_sizes; (void)out_size;

    // 1) embed
    {
        int total = (int)XE_N;
        embed_kernel<<<(total + 255) / 256, 256, 0, stream>>>(x, xe);
    }

    // 2) layer 0 (CIN=24)
    for (int t = 0; t < Tn; ++t) {
        lstm_step_gemm<CEMBn><<<dim3(256, 2), 256, 0, stream>>>(
            xe, wx0f, wh0f, b0f, wx0b, wh0b, b0b, h0, cws, t);
    }

    // 3) layer 1 (CIN=128)
    for (int t = 0; t < Tn; ++t) {
        lstm_step_gemm<128><<<dim3(256, 2), 256, 0, stream>>>(
            h0, wx1f, wh1f, b1f, wx1b, wh1b, b1b, h1, cws, t);
    }

    // 4) output conv
    out_conv<<<(Bn * Tn * Hn * Wn + 255) / 256, 256, 0, stream>>>(h1, wout, bout, out);
}

// Round 4
// 2445.575 us; speedup vs baseline: 8.0804x; 2.3357x over previous
//
#include <hip/hip_runtime.h>
#include <math.h>

// Problem constants
#define Bn   16
#define TINn 112
#define Hn   16
#define Wn   16
#define CINn 6
#define Tn   28
#define CEMBn 24

typedef float  f32x4  __attribute__((ext_vector_type(4)));
typedef short  bf16x8 __attribute__((ext_vector_type(8)));

__device__ __forceinline__ ushort f2bf(float v) {
    uint u = __float_as_uint(v);
    uint r = (u + 0x7fffu + ((u >> 16) & 1u)) >> 16;   // RNE
    return (ushort)r;
}
__device__ __forceinline__ float bf2f(ushort u) {
    return __uint_as_float((uint)u << 16);
}

// ---------------- embed: x[B,112,16,16,6] -> xe_hi/lo[B,28,16,16,24] (bf16 split) ----------------
__global__ void embed2(const float* __restrict__ x,
                       ushort* __restrict__ hi, ushort* __restrict__ lo) {
    int idx = blockIdx.x * 256 + threadIdx.x;
    const int total = Bn * Tn * Hn * Wn * CEMBn;
    if (idx >= total) return;
    int ce = idx % CEMBn;
    int r = idx / CEMBn;
    int w = r % Wn; r /= Wn;
    int h = r % Hn; r /= Hn;
    int t = r % Tn;
    int b = r / Tn;
    int ti = t * 4 + ce / CINn;
    int ci = ce % CINn;
    float v = x[(((b * TINn + ti) * Hn + h) * Wn + w) * CINn + ci];
    ushort a = f2bf(v);
    hi[idx] = a;
    lo[idx] = f2bf(v - bf2f(a));
}

// ---------------- weight prep: fp32 [tap][K][256] -> bf16 [tap][256][KP] (transposed, zero-padded) ----------------
__global__ void prep_w(const float* __restrict__ src, ushort* __restrict__ dst, int K, int KP) {
    int i = blockIdx.x * 256 + threadIdx.x;
    int total = 9 * 256 * KP;
    if (i >= total) return;
    int k = i % KP;
    int n = (i / KP) & 255;
    int tap = i / (KP * 256);
    float v = (k < K) ? src[((size_t)(tap * K + k)) * 256 + n] : 0.0f;
    dst[i] = f2bf(v);           // flat i == ((tap*256)+n)*KP + k
}

// ---------------- one ConvLSTM timestep via MFMA ----------------
// Block: 16 spatial (one image row: b,h) x 256 gate channels. 4 waves, wave w = n in [64w,64w+64).
// A (im2col, 16 rows x 32 k) hi/lo + B (weights, 256 n x 32 k) staged in LDS, double-buffered.
// z accumulated fp32 in MFMA regs: z = sum_chunks (A_hi + A_lo) * B.
template<int CINX, bool XLO, bool HLO>
__global__ __launch_bounds__(256)
void lstm_step_mfma(const ushort* __restrict__ ax_hi, const ushort* __restrict__ ax_lo,
                    const ushort* __restrict__ wTx_f, const ushort* __restrict__ wTx_b,
                    const ushort* __restrict__ wTh_f, const ushort* __restrict__ wTh_b,
                    const float* __restrict__ bias_f, const float* __restrict__ bias_b,
                    ushort* __restrict__ hout_hi, ushort* __restrict__ hout_lo,
                    float* __restrict__ c_ws, int t)
{
    constexpr int NCX = (CINX + 31) / 32;    // x2h K-chunks per tap
    constexpr int KPX = NCX * 32;            // padded x2h K per tap

    __shared__ ushort Ab[2][2][16 * 40];     // [buf][hi/lo][row*40 + k]
    __shared__ ushort Bb[2][256 * 40];       // [buf][n*40 + k]
    __shared__ float  Zs[256][17];

    const int tid = threadIdx.x;
    const int dir = blockIdx.y;
    const int b   = blockIdx.x >> 4;
    const int h   = blockIdx.x & 15;
    const int t_orig = dir ? (Tn - 1 - t) : t;

    const ushort* wTx  = dir ? wTx_b : wTx_f;
    const ushort* wTh  = dir ? wTh_b : wTh_f;
    const float*  bias = dir ? bias_b : bias_f;

    const int kh0  = (h == 0) ? 1 : 0;
    const int khn  = ((h == 15) ? 2 : 3) - kh0;
    const int ntap = khn * 3;
    const int nx   = ntap * NCX;
    const int nh   = (t > 0) ? ntap * 2 : 0;
    const int n_chunks = nx + nh;

    struct CP {
        const ushort* ahi; const ushort* alo; const ushort* wrow;
        int astride, KP, dw, validj; bool haslo;
    };
    auto mkparams = [&](int i) {
        CP P;
        if (i < nx) {
            int ti = i / NCX, cc = i - ti * NCX;
            int t3 = ti / 3;
            int kh = kh0 + t3, kw = ti - t3 * 3;
            int hh = h + kh - 1;
            size_t rb = ((size_t)(b * Tn + t_orig) * 16 + hh) * 16;
            P.ahi = ax_hi + rb * CINX + cc * 32;
            P.alo = XLO ? (ax_lo + rb * CINX + cc * 32) : (const ushort*)nullptr;
            P.astride = CINX;
            P.validj  = (CINX == 24) ? 3 : 4;
            P.dw = kw;
            P.haslo = XLO;
            P.wrow = wTx + (size_t)((kh * 3 + kw) * 256) * KPX + cc * 32;
            P.KP = KPX;
        } else {
            int ii = i - nx;
            int ti = ii >> 1, cc = ii & 1;
            int t3 = ti / 3;
            int kh = kh0 + t3, kw = ti - t3 * 3;
            int hh = h + kh - 1;
            int tp = t_orig + (dir ? 1 : -1);
            size_t rb = ((size_t)(b * Tn + tp) * 16 + hh) * 16;
            P.ahi = hout_hi + rb * 128 + dir * 64 + cc * 32;
            P.alo = HLO ? (hout_lo + rb * 128 + dir * 64 + cc * 32) : (const ushort*)nullptr;
            P.astride = 128;
            P.validj  = 4;
            P.dw = kw;
            P.haslo = HLO;
            P.wrow = wTh + (size_t)((kh * 3 + kw) * 256) * 64 + cc * 32;
            P.KP = 64;
        }
        return P;
    };

    // staging thread mapping
    const int  s_row = tid >> 3;          // 0..31 (only tid<128 used: rows 0..15)
    const int  s_j   = (tid >> 1) & 3;    // 16B slot within 32-k row
    const int  s_hl  = tid & 1;           // hi/lo
    const bool s_act = tid < 128;

    float4 rA, rB0, rB1, rB2, rB3;
    auto issue = [&](const CP& P) {
        const ushort* wr = P.wrow + (size_t)tid * P.KP;
        rB0 = *(const float4*)(wr);
        rB1 = *(const float4*)(wr + 8);
        rB2 = *(const float4*)(wr + 16);
        rB3 = *(const float4*)(wr + 24);
        rA = make_float4(0.f, 0.f, 0.f, 0.f);
        if (s_act && (s_hl == 0 || P.haslo)) {
            int ww = s_row + P.dw - 1;
            if ((unsigned)ww < 16u && s_j < P.validj) {
                const ushort* src = (s_hl ? P.alo : P.ahi) + (size_t)ww * P.astride + s_j * 8;
                rA = *(const float4*)src;
            }
        }
    };
    auto commit = [&](const CP& P, int buf) {
        float4* bd = (float4*)&Bb[buf][tid * 40];
        bd[0] = rB0; bd[1] = rB1; bd[2] = rB2; bd[3] = rB3;
        if (s_act && (s_hl == 0 || P.haslo))
            *(float4*)&Ab[buf][s_hl][s_row * 40 + s_j * 8] = rA;
    };

    // MFMA fragment indices
    const int lane = tid & 63, wv = tid >> 6;
    const int fr = lane & 15, kg = lane >> 4;

    f32x4 acc0 = {0.f,0.f,0.f,0.f}, acc1 = {0.f,0.f,0.f,0.f};
    f32x4 acc2 = {0.f,0.f,0.f,0.f}, acc3 = {0.f,0.f,0.f,0.f};

    auto compute = [&](bool haslo, int buf) {
        bf16x8 ahi = *(const bf16x8*)&Ab[buf][0][fr * 40 + kg * 8];
        bf16x8 alo = {};
        if (haslo) alo = *(const bf16x8*)&Ab[buf][1][fr * 40 + kg * 8];
        const ushort* bbase = &Bb[buf][(wv * 64 + fr) * 40 + kg * 8];
        bf16x8 b0 = *(const bf16x8*)(bbase);
        bf16x8 b1 = *(const bf16x8*)(bbase + 16 * 40);
        bf16x8 b2 = *(const bf16x8*)(bbase + 32 * 40);
        bf16x8 b3 = *(const bf16x8*)(bbase + 48 * 40);
        acc0 = __builtin_amdgcn_mfma_f32_16x16x32_bf16(ahi, b0, acc0, 0, 0, 0);
        acc1 = __builtin_amdgcn_mfma_f32_16x16x32_bf16(ahi, b1, acc1, 0, 0, 0);
        acc2 = __builtin_amdgcn_mfma_f32_16x16x32_bf16(ahi, b2, acc2, 0, 0, 0);
        acc3 = __builtin_amdgcn_mfma_f32_16x16x32_bf16(ahi, b3, acc3, 0, 0, 0);
        if (haslo) {
            acc0 = __builtin_amdgcn_mfma_f32_16x16x32_bf16(alo, b0, acc0, 0, 0, 0);
            acc1 = __builtin_amdgcn_mfma_f32_16x16x32_bf16(alo, b1, acc1, 0, 0, 0);
            acc2 = __builtin_amdgcn_mfma_f32_16x16x32_bf16(alo, b2, acc2, 0, 0, 0);
            acc3 = __builtin_amdgcn_mfma_f32_16x16x32_bf16(alo, b3, acc3, 0, 0, 0);
        }
    };

    // pipelined chunk loop (double-buffered LDS, 1 barrier per chunk)
    CP cur = mkparams(0);
    issue(cur);
    commit(cur, 0);
    __syncthreads();
    for (int i = 0; i < n_chunks; ++i) {
        const int buf = i & 1;
        const bool hav = (i + 1 < n_chunks);
        CP nxt;
        if (hav) { nxt = mkparams(i + 1); issue(nxt); }
        compute(cur.haslo, buf);
        if (hav) commit(nxt, buf ^ 1);
        __syncthreads();
        if (hav) cur = nxt;
    }

    // ---- scatter z to LDS: Zs[n][m] ----
    #pragma unroll
    for (int r = 0; r < 4; ++r) {
        Zs[wv * 64 +      fr][kg * 4 + r] = acc0[r];
        Zs[wv * 64 + 16 + fr][kg * 4 + r] = acc1[r];
        Zs[wv * 64 + 32 + fr][kg * 4 + r] = acc2[r];
        Zs[wv * 64 + 48 + fr][kg * 4 + r] = acc3[r];
    }
    __syncthreads();

    // ---- gates + cell update ----
    const int m  = tid >> 4;            // w coordinate
    const int f0 = (tid & 15) << 2;     // filter quad

    float zz[4][4];
    #pragma unroll
    for (int g = 0; g < 4; ++g) {
        const float4 bq = *(const float4*)(bias + (g << 6) + f0);
        zz[g][0] = Zs[(g << 6) + f0 + 0][m] + bq.x;
        zz[g][1] = Zs[(g << 6) + f0 + 1][m] + bq.y;
        zz[g][2] = Zs[(g << 6) + f0 + 2][m] + bq.z;
        zz[g][3] = Zs[(g << 6) + f0 + 3][m] + bq.w;
    }

    float* cp = c_ws + ((size_t)((dir * 16 + b) * 256) + (h << 4) + m) * 64 + f0;
    float cov[4] = {0.f, 0.f, 0.f, 0.f};
    if (t > 0) {
        const float4 cold = *(const float4*)cp;
        cov[0] = cold.x; cov[1] = cold.y; cov[2] = cold.z; cov[3] = cold.w;
    }

    float cn[4], hn[4];
    #pragma unroll
    for (int i = 0; i < 4; ++i) {
        const float gi = 1.0f / (1.0f + expf(-zz[0][i]));
        const float gf = 1.0f / (1.0f + expf(-zz[1][i]));
        const float gg = tanhf(zz[2][i]);
        const float go = 1.0f / (1.0f + expf(-zz[3][i]));
        const float c  = gf * cov[i] + gi * gg;
        cn[i] = c;
        hn[i] = go * tanhf(c);
    }
    *(float4*)cp = make_float4(cn[0], cn[1], cn[2], cn[3]);

    const size_t hidx = (((size_t)b * Tn + t_orig) * 256 + (h << 4) + m) * 128 + (dir << 6) + f0;
    ushort4 hhi;
    hhi.x = f2bf(hn[0]); hhi.y = f2bf(hn[1]); hhi.z = f2bf(hn[2]); hhi.w = f2bf(hn[3]);
    *(ushort4*)&hout_hi[hidx] = hhi;
    if (HLO) {
        ushort4 hlo;
        hlo.x = f2bf(hn[0] - bf2f(hhi.x));
        hlo.y = f2bf(hn[1] - bf2f(hhi.y));
        hlo.z = f2bf(hn[2] - bf2f(hhi.z));
        hlo.w = f2bf(hn[3] - bf2f(hhi.w));
        *(ushort4*)&hout_lo[hidx] = hlo;
    }
}

// ---------------- final TimeDistributed Conv2D: h1_hi bf16 [B,T,H,W,128] -> [B,T,H,W,1] fp32 ----------------
__global__ void out_conv(const ushort* __restrict__ h1,
                         const float* __restrict__ wout,
                         const float* __restrict__ bout,
                         float* __restrict__ out) {
    int idx = blockIdx.x * 256 + threadIdx.x;
    if (idx >= Bn * Tn * Hn * Wn) return;
    int w = idx & 15;
    int h = (idx >> 4) & 15;
    int r = idx >> 8;
    int t = r % Tn;
    int b = r / Tn;

    float acc = bout[0];
    for (int kh = 0; kh < 3; ++kh) {
        int hh = h + kh - 1;
        if ((unsigned)hh >= 16u) continue;
        for (int kw = 0; kw < 3; ++kw) {
            int ww = w + kw - 1;
            if ((unsigned)ww >= 16u) continue;
            const ushort* hp = h1 + (((size_t)b * Tn + t) * 256 + hh * 16 + ww) * 128;
            const float* wp = wout + (kh * 3 + kw) * 128;
            #pragma unroll 4
            for (int v = 0; v < 16; ++v) {
                uint4 q = *(const uint4*)(hp + v * 8);
                acc = fmaf(bf2f((ushort)(q.x & 0xffff)), wp[v * 8 + 0], acc);
                acc = fmaf(bf2f((ushort)(q.x >> 16)),    wp[v * 8 + 1], acc);
                acc = fmaf(bf2f((ushort)(q.y & 0xffff)), wp[v * 8 + 2], acc);
                acc = fmaf(bf2f((ushort)(q.y >> 16)),    wp[v * 8 + 3], acc);
                acc = fmaf(bf2f((ushort)(q.z & 0xffff)), wp[v * 8 + 4], acc);
                acc = fmaf(bf2f((ushort)(q.z >> 16)),    wp[v * 8 + 5], acc);
                acc = fmaf(bf2f((ushort)(q.w & 0xffff)), wp[v * 8 + 6], acc);
                acc = fmaf(bf2f((ushort)(q.w >> 16)),    wp[v * 8 + 7], acc);
            }
        }
    }
    out[idx] = acc;
}

extern "C" void kernel_launch(void* const* d_in, const int* in_sizes, int n_in,
                              void* d_out, int out_size, void* d_ws, size_t ws_size,
                              hipStream_t stream) {
    const float* x    = (const float*)d_in[0];
    const float* wx0f = (const float*)d_in[1];
    const float* wh0f = (const float*)d_in[2];
    const float* b0f  = (const float*)d_in[3];
    const float* wx0b = (const float*)d_in[4];
    const float* wh0b = (const float*)d_in[5];
    const float* b0b  = (const float*)d_in[6];
    const float* wx1f = (const float*)d_in[7];
    const float* wh1f = (const float*)d_in[8];
    const float* b1f  = (const float*)d_in[9];
    const float* wx1b = (const float*)d_in[10];
    const float* wh1b = (const float*)d_in[11];
    const float* b1b  = (const float*)d_in[12];
    const float* wout = (const float*)d_in[13];
    const float* bout = (const float*)d_in[14];
    float* out = (float*)d_out;
    (void)in_sizes; (void)n_in; (void)out_size; (void)ws_size;

    // ---- workspace layout (ushort elements unless noted) ----
    const size_t XE_N = (size_t)Bn * Tn * Hn * Wn * CEMBn;   //  2,752,512
    const size_t H_N  = (size_t)Bn * Tn * Hn * Wn * 128;     // 14,680,064
    ushort* xe_hi = (ushort*)d_ws;
    ushort* xe_lo = xe_hi + XE_N;
    ushort* h0_hi = xe_lo + XE_N;
    ushort* h0_lo = h0_hi + H_N;
    ushort* h1_hi = h0_lo + H_N;
    ushort* wx0fT = h1_hi + H_N;            // 9*256*32  =  73,728 each
    ushort* wx0bT = wx0fT + 9 * 256 * 32;
    ushort* wh0fT = wx0bT + 9 * 256 * 32;   // 9*256*64  = 147,456 each
    ushort* wh0bT = wh0fT + 9 * 256 * 64;
    ushort* wh1fT = wh0bT + 9 * 256 * 64;
    ushort* wh1bT = wh1fT + 9 * 256 * 64;
    ushort* wx1fT = wh1bT + 9 * 256 * 64;   // 9*256*128 = 294,912 each
    ushort* wx1bT = wx1fT + 9 * 256 * 128;
    float*  cws   = (float*)(wx1bT + 9 * 256 * 128);  // 2*16*256*64 fp32
    // total ≈ 103.8 MB

    // ---- weight prep (bf16, transposed [tap][n][k], zero-padded k) ----
    prep_w<<<(9 * 256 * 32  + 255) / 256, 256, 0, stream>>>(wx0f, wx0fT, 24, 32);
    prep_w<<<(9 * 256 * 32  + 255) / 256, 256, 0, stream>>>(wx0b, wx0bT, 24, 32);
    prep_w<<<(9 * 256 * 64  + 255) / 256, 256, 0, stream>>>(wh0f, wh0fT, 64, 64);
    prep_w<<<(9 * 256 * 64  + 255) / 256, 256, 0, stream>>>(wh0b, wh0bT, 64, 64);
    prep_w<<<(9 * 256 * 64  + 255) / 256, 256, 0, stream>>>(wh1f, wh1fT, 64, 64);
    prep_w<<<(9 * 256 * 64  + 255) / 256, 256, 0, stream>>>(wh1b, wh1bT, 64, 64);
    prep_w<<<(9 * 256 * 128 + 255) / 256, 256, 0, stream>>>(wx1f, wx1fT, 128, 128);
    prep_w<<<(9 * 256 * 128 + 255) / 256, 256, 0, stream>>>(wx1b, wx1bT, 128, 128);

    // ---- embed (hi/lo split) ----
    embed2<<<(int)((XE_N + 255) / 256), 256, 0, stream>>>(x, xe_hi, xe_lo);

    // ---- layer 0: x2h from xe (24ch), h2h from h0 (own dir) ----
    for (int t = 0; t < Tn; ++t) {
        lstm_step_mfma<24, true, true><<<dim3(256, 2), 256, 0, stream>>>(
            xe_hi, xe_lo, wx0fT, wx0bT, wh0fT, wh0bT, b0f, b0b, h0_hi, h0_lo, cws, t);
    }
    // ---- layer 1: x2h from h0 (128ch hi+lo), h2h from h1 (hi only) ----
    for (int t = 0; t < Tn; ++t) {
        lstm_step_mfma<128, true, false><<<dim3(256, 2), 256, 0, stream>>>(
            h0_hi, h0_lo, wx1fT, wx1bT, wh1fT, wh1bT, b1f, b1b, h1_hi, nullptr, cws, t);
    }

    // ---- output conv ----
    out_conv<<<(Bn * Tn * Hn * Wn + 255) / 256, 256, 0, stream>>>(h1_hi, wout, bout, out);
}